// Round 5
// baseline (352.331 us; speedup 1.0000x reference)
//
#include <hip/hip_runtime.h>

// ---------------------------------------------------------------------------
// MultiheadCosformerAttention: B=4, L=4096, E=1024, H=16, hd=64
// Round 9: two K-loop schedules both plateaued at 33-35% MfmaUtil with
//          1 block/CU (128 KiB LDS) -> the exposed per-round prologue/epilogue
//          storms + whole-CU barrier stalls are the bottleneck, not the
//          schedule. New geometry: BM=128 BN=256 BK=32, 48 KiB LDS,
//          launch_bounds(512,4) -> 2 blocks/CU; one block's K-loop hides the
//          other's stalls (m114 mechanism). Same counted-vmcnt 2-barrier loop.
// ---------------------------------------------------------------------------

typedef unsigned short u16;
typedef unsigned int u32;
typedef __attribute__((ext_vector_type(8))) __bf16 bf16x8;
typedef __attribute__((ext_vector_type(4))) float f32x4;

#define PI_HALF 1.57079632679489662f
#define EPS_Z 1e-4f

__device__ __forceinline__ u16 f32_to_bf16(float f) {
    union { float f; unsigned int u; } x; x.f = f;
    unsigned int lsb = (x.u >> 16) & 1u;
    x.u += 0x7fffu + lsb;                 // round-to-nearest-even
    return (u16)(x.u >> 16);
}

typedef __attribute__((address_space(1))) void amdgpu_global_t;
typedef __attribute__((address_space(3))) void amdgpu_lds_t;
__device__ __forceinline__ void async_load16(const u16* g, u16* l) {
    __builtin_amdgcn_global_load_lds((amdgpu_global_t*)g, (amdgpu_lds_t*)l, 16, 0, 0);
}

// ---------------------------------------------------------------------------
// fp32 -> bf16 converts
// ---------------------------------------------------------------------------
__global__ __launch_bounds__(256) void cvt_bf16(const float* __restrict__ in,
                                                u16* __restrict__ out, int n4) {
    int i = blockIdx.x * 256 + threadIdx.x;
    if (i >= n4) return;
    float4 f = ((const float4*)in)[i];
    ushort4 o;
    o.x = f32_to_bf16(f.x); o.y = f32_to_bf16(f.y);
    o.z = f32_to_bf16(f.z); o.w = f32_to_bf16(f.w);
    ((ushort4*)out)[i] = o;
}

__global__ __launch_bounds__(256) void cvt_w4(const float* __restrict__ w0,
                                              const float* __restrict__ w1,
                                              const float* __restrict__ w2,
                                              const float* __restrict__ w3,
                                              u16* __restrict__ wcat) {
    const float* src = (blockIdx.y == 0) ? w0 : (blockIdx.y == 1) ? w1
                     : (blockIdx.y == 2) ? w2 : w3;
    u16* dst = wcat + (size_t)blockIdx.y * 1048576;
    int i = blockIdx.x * 256 + threadIdx.x;
    float4 f = ((const float4*)src)[i];
    ushort4 o;
    o.x = f32_to_bf16(f.x); o.y = f32_to_bf16(f.y);
    o.z = f32_to_bf16(f.z); o.w = f32_to_bf16(f.w);
    ((ushort4*)dst)[i] = o;
}

// ---------------------------------------------------------------------------
// 128x256 / BK=32 / 8-wave GEMM core, 2 blocks/CU. A and B K-major, K=1024,
// 32 K-tiles. LDS 48 KiB: As[2][128][32], Bs[2][256][32] u16.
// Swizzle (BK=32, 4 groups of 8 u16 per row): LDS[row][p] holds global
// colgroup p ^ ((row>>1)&3); applied inverse on the staging SOURCE address
// (global_load_lds writes linearly) and on the ds_read address. Read group
// = quad ^ ((l15>>1)&3) -> lane-constant; 2 lanes/bank (free).
// Per K-tile: 8 ds_read_b128, 16 MFMA, 3 global_load_lds, 2 barriers,
// vmcnt(3) (t+1 resident, t+2 in flight — never 0 mid-loop).
// ---------------------------------------------------------------------------
__device__ __forceinline__ void gemm128_core(const u16* __restrict__ Abase,
                                             const u16* __restrict__ Bbase,
                                             u16* As, u16* Bs,
                                             f32x4 (&acc)[4][4]) {
    const int tid  = threadIdx.x;
    const int wave = tid >> 6;
    const int lane = tid & 63;
    const int quad = lane >> 4;
    const int l15  = lane & 15;
    const int wr   = wave >> 2;                 // 0..1 -> rows [wr*64, +64)
    const int wc   = wave & 3;                  // 0..3 -> cols [wc*64, +64)
    const int srow = tid >> 2;                  // staging row 0..127
    const int scg  = (tid & 3) ^ ((srow >> 1) & 3);   // pre-swizzled src group
    const int sg   = (quad ^ ((l15 >> 1) & 3)) * 8;   // read col offset (u16)

    const u16* Ag = Abase + ((long)srow << 10) + scg * 8;
    const u16* Bg = Bbase + ((long)srow << 10) + scg * 8;

    auto stage = [&](int cur, int t) {
        async_load16(Ag + (t << 5),              As + cur * 4096 + tid * 8);
        async_load16(Bg + (t << 5),              Bs + cur * 8192 + tid * 8);
        async_load16(Bg + (1 << 17) + (t << 5),  Bs + cur * 8192 + 4096 + tid * 8);
    };
    auto rdA = [&](int cur, int mf) -> bf16x8 {
        return *(const bf16x8*)(As + cur * 4096 + (wr * 64 + mf * 16 + l15) * 32 + sg);
    };
    auto rdB = [&](int cur, int nf) -> bf16x8 {
        return *(const bf16x8*)(Bs + cur * 8192 + (wc * 64 + nf * 16 + l15) * 32 + sg);
    };

    stage(0, 0);
    stage(1, 1);
    asm volatile("s_waitcnt vmcnt(3)" ::: "memory");   // tile 0 resident
    __builtin_amdgcn_s_barrier();

#pragma unroll 1
    for (int t = 0; t < 32; ++t) {
        const int cur = t & 1;
        bf16x8 a[4], b[4];
#pragma unroll
        for (int i = 0; i < 4; ++i) a[i] = rdA(cur, i);
        b[0] = rdB(cur, 0); b[1] = rdB(cur, 1);
        __builtin_amdgcn_s_setprio(1);
#pragma unroll
        for (int i = 0; i < 4; ++i) {
            acc[i][0] = __builtin_amdgcn_mfma_f32_16x16x32_bf16(a[i], b[0], acc[i][0], 0, 0, 0);
            acc[i][1] = __builtin_amdgcn_mfma_f32_16x16x32_bf16(a[i], b[1], acc[i][1], 0, 0, 0);
        }
        __builtin_amdgcn_s_setprio(0);
        b[2] = rdB(cur, 2); b[3] = rdB(cur, 3);
        __builtin_amdgcn_s_setprio(1);
#pragma unroll
        for (int i = 0; i < 4; ++i) {
            acc[i][2] = __builtin_amdgcn_mfma_f32_16x16x32_bf16(a[i], b[2], acc[i][2], 0, 0, 0);
            acc[i][3] = __builtin_amdgcn_mfma_f32_16x16x32_bf16(a[i], b[3], acc[i][3], 0, 0, 0);
        }
        __builtin_amdgcn_s_setprio(0);

        __builtin_amdgcn_s_barrier();        // all waves done reading cur
        asm volatile("" ::: "memory");       // stages must stay below barrier
        if (t < 30) {
            stage(cur, t + 2);
            asm volatile("s_waitcnt vmcnt(3)" ::: "memory");  // t+1 resident
        } else {
            asm volatile("s_waitcnt vmcnt(0)" ::: "memory");
        }
        __builtin_amdgcn_s_barrier();
        asm volatile("" ::: "memory");
    }
}

// ---------------------------------------------------------------------------
// Fused QKV GEMM. Wcat = [3072][1024] (Wq;Wk;Wv). Grid: 1536 blocks of 512
// (128 M-tiles x 12 N-tiles), 2 blocks/CU. Epilogue: group-XOR LDS bounce
// through Bs -> conflict-free writes + fully-coalesced 512B-run stores.
// ---------------------------------------------------------------------------
__global__ __launch_bounds__(512, 4) void gemm_qkv(const u16* __restrict__ A,
                                                   const u16* __restrict__ Wcat,
                                                   const float* __restrict__ bq,
                                                   const float* __restrict__ bk,
                                                   const float* __restrict__ bv,
                                                   u16* __restrict__ qo,
                                                   u16* __restrict__ ko,
                                                   u16* __restrict__ vo) {
    __shared__ __align__(16) u16 As[8192];      // 16 KiB
    __shared__ __align__(16) u16 Bs[16384];     // 32 KiB
    const int bid = blockIdx.x;                 // 1536 = 8 * 192
    const int swz = (bid & 7) * 192 + (bid >> 3);   // XCD swizzle, bijective
    const int bx  = swz / 12;
    const int byy = swz - bx * 12;
    const long tileM = (long)bx * 128;

    f32x4 acc[4][4] = {};
    gemm128_core(A + (tileM << 10), Wcat + ((long)byy << 18), As, Bs, acc);

    const int tid  = (int)threadIdx.x;
    const int wave = tid >> 6;
    const int lane = tid & 63;
    const int quad = lane >> 4, l15 = lane & 15;
    const int wr = wave >> 2, wc = wave & 3;
    const int mat = byy >> 2;                   // 0:q 1:k 2:v
    const float* bias = (mat == 0) ? bq : (mat == 1) ? bk : bv;
    u16* outp = (mat == 0) ? qo : (mat == 1) ? ko : vo;
    const bool relu = (mat < 2);
    const int ncol0 = (byy & 3) * 256;

    // bounce passes: wr==pass waves dump [64 rows x 256 cols] into Bs,
    // group-swizzled gs = g ^ (quad<<1) -> 8 distinct groups/instr, 2-way max.
#pragma unroll 1
    for (int pass = 0; pass < 2; ++pass) {
        __syncthreads();
        if (wr == pass) {
#pragma unroll
            for (int mf = 0; mf < 4; ++mf)
#pragma unroll
                for (int nf = 0; nf < 4; ++nf) {
                    const int col = wc * 64 + nf * 16 + l15;
                    const float bb = bias[ncol0 + col];
                    const int gs = ((col >> 3) ^ (quad << 1)) * 8 + (col & 7);
#pragma unroll
                    for (int r = 0; r < 4; ++r) {
                        const int row = mf * 16 + quad * 4 + r;
                        float v = acc[mf][nf][r] + bb;
                        if (relu) v = fmaxf(v, 0.0f);
                        Bs[row * 256 + gs] = f32_to_bf16(v);
                    }
                }
        }
        __syncthreads();
        const int rloc = tid >> 5, gg = tid & 31;
        const long gr0 = tileM + pass * 64;
#pragma unroll
        for (int it = 0; it < 4; ++it) {
            const int row = it * 16 + rloc;
            const int gsr = gg ^ (((row >> 2) & 3) << 1);
            uint4 t4 = *(const uint4*)&Bs[row * 256 + gsr * 8];
            *(uint4*)&outp[(gr0 + row) * 1024 + ncol0 + gg * 8] = t4;
        }
    }
}

// ---------------------------------------------------------------------------
// Output-projection GEMM (fp32 out). Grid: 512 blocks of 512 (128 M x 4 N),
// 2 blocks/CU. fp32 stores are 64B-contiguous per 16 lanes — kept direct.
// ---------------------------------------------------------------------------
__global__ __launch_bounds__(512, 4) void gemm_o(const u16* __restrict__ A,
                                                 const u16* __restrict__ Bw,
                                                 const float* __restrict__ bias,
                                                 float* __restrict__ Cout) {
    __shared__ __align__(16) u16 As[8192];
    __shared__ __align__(16) u16 Bs[16384];
    const int bid = blockIdx.x;                 // 512 = 8 * 64
    const int swz = (bid & 7) * 64 + (bid >> 3);
    const int bx  = swz >> 2;
    const int byy = swz & 3;
    const long tileM = (long)bx * 128;
    const long tileN = (long)byy * 256;

    f32x4 acc[4][4] = {};
    gemm128_core(A + (tileM << 10), Bw + (tileN << 10), As, Bs, acc);

    const int wave = (int)threadIdx.x >> 6;
    const int lane = (int)threadIdx.x & 63;
    const int quad = lane >> 4, l15 = lane & 15;
    const int wr = wave >> 2, wc = wave & 3;
#pragma unroll
    for (int nf = 0; nf < 4; ++nf) {
        const long n = tileN + wc * 64 + nf * 16 + l15;
        const float bb = bias[n];
#pragma unroll
        for (int mf = 0; mf < 4; ++mf) {
            const long m0 = tileM + wr * 64 + mf * 16 + quad * 4;
#pragma unroll
            for (int r = 0; r < 4; ++r)
                Cout[(m0 + r) * 1024 + n] = acc[mf][nf][r] + bb;
        }
    }
}

// ---------------------------------------------------------------------------
// Stage C (MFMA): per (chunk, head): part[d2=128][n=80] = k_^T @ [v | 1 | 0]
//   over K = 512 l's. Register prefetch of next-kt global loads hides the
//   L2/L3 latency under the LDS-write + compute of the current kt.
// grid (8, 64), 256 threads = 4 waves.
// part layout: [chunk8][head64][128][80] f32.
// ---------------------------------------------------------------------------
__global__ __launch_bounds__(256) void kv_mfma(const u16* __restrict__ kmat,
                                               const u16* __restrict__ vmat,
                                               float* __restrict__ part) {
    __shared__ u16 Ak[64 * 40];   // [d 64][l 32 +8 pad], stride 80B (16B-mult)
    __shared__ u16 Bv[64 * 40];
    const int tid = threadIdx.x;
    const int wave = tid >> 6, lane = tid & 63;
    const int quad = lane >> 4, l15 = lane & 15;
    const int head = blockIdx.y;
    const int b = head >> 4, h = head & 15;
    const int l0 = blockIdx.x * 512;
    const int sl = tid >> 3;          // staging row l 0..31
    const int sc8 = tid & 7;          // staging d-octet 0..7
    const int scol = sl ^ ((sc8 & 3) << 3);   // XOR swizzle col
    const int krow_base = (wave & 1) * 32;
    const bool use_cos = (wave >> 1) != 0;
    const int mbase = wave * 32;

    // sin/cos for l = l0 + kt*32 + quad*8 + e, advanced by rotation each tile
    float sv[8], cv[8];
#pragma unroll
    for (int e = 0; e < 8; e++) {
        float ang = (PI_HALF / 4096.0f) * (float)(l0 + quad * 8 + e + 1);
        sv[e] = sinf(ang); cv[e] = cosf(ang);
    }
    const float cD = 0.9999247018391445f;   // cos(pi/256)
    const float sD = 0.0122715382857199f;   // sin(pi/256)

    bf16x8 onesf;
#pragma unroll
    for (int e = 0; e < 8; e++)
        onesf[e] = (l15 == 0) ? (__bf16)1.0f : (__bf16)0.0f;

    f32x4 acc[2][5] = {};

    long row = ((long)b * 4096 + l0 + sl) * 1024 + h * 64 + sc8 * 8;
    uint4 kk = *(const uint4*)(kmat + row);
    uint4 vv = *(const uint4*)(vmat + row);

    for (int kt = 0; kt < 16; kt++) {
        uint4 kk_n = {}, vv_n = {};
        if (kt < 15) {                       // prefetch next kt before writes
            row += 32 * 1024;
            kk_n = *(const uint4*)(kmat + row);
            vv_n = *(const uint4*)(vmat + row);
        }
        const u16* kp = (const u16*)&kk;
        const u16* vp = (const u16*)&vv;
#pragma unroll
        for (int e = 0; e < 8; e++) {
            const int d = sc8 * 8 + e;
            Ak[d * 40 + scol] = kp[e];
            Bv[d * 40 + scol] = vp[e];
        }
        __syncthreads();

        bf16x8 af[2];
#pragma unroll
        for (int i = 0; i < 2; i++) {
            const int d = krow_base + i * 16 + l15;
            const int q2 = (quad ^ ((d >> 3) & 3)) * 8;
            bf16x8 raw = *(const bf16x8*)&Ak[d * 40 + q2];
            bf16x8 sc;
#pragma unroll
            for (int e = 0; e < 8; e++)
                sc[e] = (__bf16)((float)raw[e] * (use_cos ? cv[e] : sv[e]));
            af[i] = sc;
        }
        bf16x8 bfr[5];
#pragma unroll
        for (int j = 0; j < 4; j++) {
            const int n = j * 16 + l15;
            const int q2 = (quad ^ ((n >> 3) & 3)) * 8;
            bfr[j] = *(const bf16x8*)&Bv[n * 40 + q2];
        }
        bfr[4] = onesf;
#pragma unroll
        for (int i = 0; i < 2; i++)
#pragma unroll
            for (int j = 0; j < 5; j++)
                acc[i][j] = __builtin_amdgcn_mfma_f32_16x16x32_bf16(
                    af[i], bfr[j], acc[i][j], 0, 0, 0);

        // advance angles by pi/256
#pragma unroll
        for (int e = 0; e < 8; e++) {
            const float ns = sv[e] * cD + cv[e] * sD;
            cv[e] = cv[e] * cD - sv[e] * sD;
            sv[e] = ns;
        }
        __syncthreads();
        kk = kk_n; vv = vv_n;
    }

    float* op = part + ((long)blockIdx.x * 64 + head) * 10240;
#pragma unroll
    for (int i = 0; i < 2; i++)
#pragma unroll
        for (int j = 0; j < 5; j++)
#pragma unroll
            for (int r = 0; r < 4; r++)
                op[(mbase + i * 16 + quad * 4 + r) * 80 + j * 16 + l15] = acc[i][j][r];
}

// ---------------------------------------------------------------------------
// Stage C2: sum 8 chunk-partials, transpose to Bt[head][n=80][d2=128] bf16.
// grid (4 d2-tiles of 32, 64 heads), 256 threads.
// ---------------------------------------------------------------------------
__global__ __launch_bounds__(256) void kv_reduce_t(const float* __restrict__ part,
                                                   u16* __restrict__ Bt) {
    __shared__ float accs[32 * 81];
    const int head = blockIdx.y, d2t = blockIdx.x;
    const float* bp = part + (long)head * 10240 + d2t * 32 * 80;
    for (int idx = threadIdx.x; idx < 2560; idx += 256) {
        float s = 0.0f;
#pragma unroll
        for (int c = 0; c < 8; c++) s += bp[(long)c * 655360 + idx];
        const int d2 = idx / 80, n = idx - d2 * 80;
        accs[d2 * 81 + n] = s;
    }
    __syncthreads();
    for (int idx = threadIdx.x; idx < 2560; idx += 256) {
        const int n = idx >> 5, d2 = idx & 31;
        Bt[(long)head * 10240 + n * 128 + d2t * 32 + d2] = f32_to_bf16(accs[d2 * 81 + n]);
    }
}

// ---------------------------------------------------------------------------
// Stage D: per-head MFMA GEMM: attn[l, 0..79] = q_[l, 0..127] @ Bt^T
// Epilogue: LDS-bounce for coalesced 128B-per-row dwordx4 stores.
// ---------------------------------------------------------------------------
__global__ __launch_bounds__(256) void attn_mfma(const u16* __restrict__ qb,
                                                 const u16* __restrict__ Bt,
                                                 u16* __restrict__ merged) {
    __shared__ __align__(16) u16 As[128 * 72];   // q tile [l][64], stride 72
    __shared__ __align__(16) u16 Bs[80 * 136];   // Bt tile [n][128], stride 136
    const int tid = threadIdx.x;
    const int wave = tid >> 6, lane = tid & 63;
    const int quad = lane >> 4, l15 = lane & 15;
    const int head = blockIdx.y;
    const int b = head >> 4, h = head & 15;
    const int tm = blockIdx.x * 128;
    const long b4 = (long)b * 4096;

    for (int c = tid; c < 1024; c += 256) {
        const int row = c >> 3, c8 = c & 7;
        uint4 t = *(const uint4*)(qb + (b4 + tm + row) * 1024 + h * 64 + c8 * 8);
        *(uint4*)&As[row * 72 + c8 * 8] = t;
    }
    for (int c = tid; c < 1280; c += 256) {
        const int row = c >> 4, c16 = c & 15;
        uint4 t = *(const uint4*)(Bt + (long)head * 10240 + row * 128 + c16 * 8);
        *(uint4*)&Bs[row * 136 + c16 * 8] = t;
    }
    const int wm = wave * 32;
    float snl[2], csl[2];
#pragma unroll
    for (int i = 0; i < 2; i++) {
        const int l = tm + wm + i * 16 + l15;
        const float idx = PI_HALF * (float)(l + 1) * (1.0f / 4096.0f);
        snl[i] = sinf(idx); csl[i] = cosf(idx);
    }
    __syncthreads();

    f32x4 acc[2][5] = {};
#pragma unroll
    for (int kb = 0; kb < 4; kb++) {
        const int qc = (kb & 1) * 32 + quad * 8;
        bf16x8 af[2];
#pragma unroll
        for (int i = 0; i < 2; i++) {
            bf16x8 raw = *(const bf16x8*)&As[(wm + i * 16 + l15) * 72 + qc];
            const float s = (kb < 2) ? snl[i] : csl[i];
            bf16x8 sc;
#pragma unroll
            for (int e = 0; e < 8; e++) sc[e] = (__bf16)((float)raw[e] * s);
            af[i] = sc;
        }
        bf16x8 bf[5];
#pragma unroll
        for (int j = 0; j < 5; j++)
            bf[j] = *(const bf16x8*)&Bs[(j * 16 + l15) * 136 + kb * 32 + quad * 8];
#pragma unroll
        for (int i = 0; i < 2; i++)
#pragma unroll
            for (int j = 0; j < 5; j++)
                acc[i][j] = __builtin_amdgcn_mfma_f32_16x16x32_bf16(
                    af[i], bf[j], acc[i][j], 0, 0, 0);
    }

    // normalize + dump to LDS (reuse As as [128 rows][64 cols] u16)
    __syncthreads();
#pragma unroll
    for (int i = 0; i < 2; i++) {
        float z[4];
#pragma unroll
        for (int r = 0; r < 4; r++) {
            const float den = __shfl(acc[i][4][r], lane & 0x30, 64);
            z[r] = 1.0f / fmaxf(den, EPS_Z);
        }
#pragma unroll
        for (int j = 0; j < 4; j++)
#pragma unroll
            for (int r = 0; r < 4; r++) {
                const int row = wm + i * 16 + quad * 4 + r;
                As[row * 64 + j * 16 + l15] = f32_to_bf16(acc[i][j][r] * z[r]);
            }
    }
    __syncthreads();
    // coalesced copy-out: 128 rows x 128B; 256 threads = 32 rows/iter
    const int rloc = tid >> 3, c8 = (tid & 7) * 8;
#pragma unroll
    for (int it = 0; it < 4; ++it) {
        const int row = it * 32 + rloc;
        uint4 t4 = *(const uint4*)&As[row * 64 + c8];
        *(uint4*)&merged[(b4 + tm + row) * 1024 + h * 64 + c8] = t4;
    }
}

// ---------------------------------------------------------------------------
extern "C" void kernel_launch(void* const* d_in, const int* in_sizes, int n_in,
                              void* d_out, int out_size, void* d_ws, size_t ws_size,
                              hipStream_t stream) {
    (void)in_sizes; (void)n_in; (void)out_size; (void)ws_size;
    const float* x  = (const float*)d_in[0];
    const float* Wq = (const float*)d_in[1];
    const float* bq = (const float*)d_in[2];
    const float* Wk = (const float*)d_in[3];
    const float* bk = (const float*)d_in[4];
    const float* Wv = (const float*)d_in[5];
    const float* bv = (const float*)d_in[6];
    const float* Wo = (const float*)d_in[7];
    const float* bo = (const float*)d_in[8];
    float* out = (float*)d_out;

    const int M = 16384, E = 1024;
    char* ws = (char*)d_ws;
    const size_t MB = 1048576;
    u16* xb   = (u16*)(ws);              // 32 MiB; dead after QKV GEMM -> part
    u16* qb   = (u16*)(ws + 32 * MB);
    u16* kb   = (u16*)(ws + 64 * MB);    // dead after kv_mfma -> merged
    u16* vb   = (u16*)(ws + 96 * MB);
    u16* wcat = (u16*)(ws + 128 * MB);   // Wq;Wk;Wv;Wo bf16, 8 MiB
    u16* wob  = wcat + 3 * (size_t)E * E;
    u16* Btb  = (u16*)(ws + 136 * MB);   // 1.25 MiB
    float* part = (float*)xb;            // 8*64*10240*4 = 20 MiB
    u16* mergedb = kb;

    cvt_bf16<<<dim3(M * E / 4 / 256), dim3(256), 0, stream>>>(x, xb, M * E / 4);
    cvt_w4<<<dim3(E * E / 4 / 256, 4), dim3(256), 0, stream>>>(Wq, Wk, Wv, Wo, wcat);

    gemm_qkv<<<dim3(1536), dim3(512), 0, stream>>>(xb, wcat, bq, bk, bv, qb, kb, vb);

    kv_mfma<<<dim3(8, 64), dim3(256), 0, stream>>>(kb, vb, part);
    kv_reduce_t<<<dim3(4, 64), dim3(256), 0, stream>>>(part, Btb);
    attn_mfma<<<dim3(32, 64), dim3(256), 0, stream>>>(qb, Btb, mergedb);

    gemm_o<<<dim3(512), dim3(512), 0, stream>>>(mergedb, wob, bo, out);
}

// Round 6
// 341.110 us; speedup vs baseline: 1.0329x; 1.0329x over previous
//
#include <hip/hip_runtime.h>

// ---------------------------------------------------------------------------
// MultiheadCosformerAttention: B=4, L=4096, E=1024, H=16, hd=64
// Round 10: GEMM cores reverted to round-3 best (256^2, 2-barrier counted
//           vmcnt, swizzled, 343.9 us total). This round targets the middle
//           pipeline: (1) converts merged into one kernel, (2) kv_mfma moves
//           to 64-l K-tiles (half the syncthreads, same traffic),
//           (3) attn_mfma processes 256 rows/block (Bt staged once per 2
//           q-tiles, half the blocks).
// ---------------------------------------------------------------------------

typedef unsigned short u16;
typedef unsigned int u32;
typedef __attribute__((ext_vector_type(8))) __bf16 bf16x8;
typedef __attribute__((ext_vector_type(4))) float f32x4;

#define PI_HALF 1.57079632679489662f
#define EPS_Z 1e-4f

__device__ __forceinline__ u16 f32_to_bf16(float f) {
    union { float f; unsigned int u; } x; x.f = f;
    unsigned int lsb = (x.u >> 16) & 1u;
    x.u += 0x7fffu + lsb;                 // round-to-nearest-even
    return (u16)(x.u >> 16);
}

typedef __attribute__((address_space(1))) void amdgpu_global_t;
typedef __attribute__((address_space(3))) void amdgpu_lds_t;
__device__ __forceinline__ void async_load16(const u16* g, u16* l) {
    __builtin_amdgcn_global_load_lds((amdgpu_global_t*)g, (amdgpu_lds_t*)l, 16, 0, 0);
}

// ---------------------------------------------------------------------------
// fp32 -> bf16 converts, fused: blocks [0,16384) do x, [16384, 20480) do the
// four weight matrices into wcat.
// ---------------------------------------------------------------------------
__global__ __launch_bounds__(256) void cvt_all(const float* __restrict__ x,
                                               const float* __restrict__ w0,
                                               const float* __restrict__ w1,
                                               const float* __restrict__ w2,
                                               const float* __restrict__ w3,
                                               u16* __restrict__ xb,
                                               u16* __restrict__ wcat) {
    const int bid = blockIdx.x;
    const float* src;
    u16* dst;
    int i;
    if (bid < 16384) {
        src = x; dst = xb;
        i = bid * 256 + threadIdx.x;
    } else {
        const int wb = bid - 16384;
        const int wsel = wb >> 10;            // 1024 blocks per weight
        src = (wsel == 0) ? w0 : (wsel == 1) ? w1 : (wsel == 2) ? w2 : w3;
        dst = wcat + (size_t)wsel * 1048576;
        i = (wb & 1023) * 256 + threadIdx.x;
    }
    float4 f = ((const float4*)src)[i];
    ushort4 o;
    o.x = f32_to_bf16(f.x); o.y = f32_to_bf16(f.y);
    o.z = f32_to_bf16(f.z); o.w = f32_to_bf16(f.w);
    ((ushort4*)dst)[i] = o;
}

// ---------------------------------------------------------------------------
// 256x256 / BK=64 / 8-wave GEMM core, 2 barriers per K-tile (A and B K-major,
// K = 1024, 16 K-tiles). LDS 128 KiB double-buffered; XOR swizzle via
// pre-swizzled global source (bank-conflict-free, HW-verified = 0).
// Round-3 version (best measured total).
// ---------------------------------------------------------------------------
__device__ __forceinline__ void gemm256_core(const u16* __restrict__ Abase,
                                             const u16* __restrict__ Bbase,
                                             u16* As, u16* Bs,
                                             f32x4 (&acc)[8][4]) {
    const int tid  = threadIdx.x;
    const int wave = tid >> 6;
    const int lane = tid & 63;
    const int quad = lane >> 4;
    const int l15  = lane & 15;
    const int wr   = wave >> 2;           // 0..1  -> rows [wr*128, +128)
    const int wc   = wave & 3;            // 0..3  -> cols [wc*64, +64)
    const int srow = tid >> 3;            // staging row 0..63 within region
    const int scg  = (tid & 7) ^ (srow & 7);   // pre-swizzled source colgroup

    const u16* Ag = Abase + ((long)srow << 10) + scg * 8;
    const u16* Bg = Bbase + ((long)srow << 10) + scg * 8;

    auto stage = [&](const u16* g, u16* lb, int hs, int t) {
        async_load16(g + ((long)hs << 16) + (t << 6), lb + hs * 4096);
    };
    auto rdA = [&](const u16* buf, int mf, int kk) -> bf16x8 {
        const int R = wr * 128 + mf * 16 + l15;
        return *(const bf16x8*)(buf + R * 64 + ((kk * 32 + quad * 8) ^ ((R & 7) * 8)));
    };
    auto rdB = [&](const u16* buf, int nf, int kk) -> bf16x8 {
        const int R = wc * 64 + nf * 16 + l15;
        return *(const bf16x8*)(buf + R * 64 + ((kk * 32 + quad * 8) ^ ((R & 7) * 8)));
    };

    bf16x8 a[4][2], b[4][2];
    auto mfma8 = [&](int i0, int j0) {
        __builtin_amdgcn_s_setprio(1);
#pragma unroll
        for (int i = 0; i < 4; ++i)
#pragma unroll
            for (int j = 0; j < 2; ++j)
#pragma unroll
                for (int kk = 0; kk < 2; ++kk)
                    acc[i0 + i][j0 + j] = __builtin_amdgcn_mfma_f32_16x16x32_bf16(
                        a[i][kk], b[j0 + j][kk], acc[i0 + i][j0 + j], 0, 0, 0);
        __builtin_amdgcn_s_setprio(0);
    };

    // prologue: stage K-tile 0 -> buf0, K-tile 1 -> buf1 (8+8 loads)
#pragma unroll
    for (int hs = 0; hs < 4; ++hs) stage(Ag, As + wave * 512, hs, 0);
#pragma unroll
    for (int hs = 0; hs < 4; ++hs) stage(Bg, Bs + wave * 512, hs, 0);
#pragma unroll
    for (int hs = 0; hs < 4; ++hs) stage(Ag, As + 16384 + wave * 512, hs, 1);
#pragma unroll
    for (int hs = 0; hs < 4; ++hs) stage(Bg, Bs + 16384 + wave * 512, hs, 1);
    asm volatile("s_waitcnt vmcnt(8)" ::: "memory");   // tile 0 resident
    __builtin_amdgcn_s_barrier();

#pragma unroll 1
    for (int t = 0; t < 16; ++t) {
        const int cur = t & 1;
        const u16* Ab = As + cur * 16384;
        const u16* Bb = Bs + cur * 16384;
        u16* lA = As + cur * 16384 + wave * 512;
        u16* lB = Bs + cur * 16384 + wave * 512;
        const bool pf = (t < 14);

        // R1 + C1
#pragma unroll
        for (int i = 0; i < 4; ++i) { a[i][0] = rdA(Ab, i, 0); a[i][1] = rdA(Ab, i, 1); }
#pragma unroll
        for (int j = 0; j < 2; ++j) { b[j][0] = rdB(Bb, j, 0); b[j][1] = rdB(Bb, j, 1); }
        mfma8(0, 0);
        // R2 + C2
#pragma unroll
        for (int j = 2; j < 4; ++j) { b[j][0] = rdB(Bb, j, 0); b[j][1] = rdB(Bb, j, 1); }
        mfma8(0, 2);
        // R3 + C3
#pragma unroll
        for (int i = 0; i < 4; ++i) { a[i][0] = rdA(Ab, i + 4, 0); a[i][1] = rdA(Ab, i + 4, 1); }
        mfma8(4, 0);

        __builtin_amdgcn_s_barrier();        // all waves done reading cur
        asm volatile("" ::: "memory");       // stages must stay below barrier
        if (pf) {
#pragma unroll
            for (int hs = 0; hs < 4; ++hs) stage(Bg, lB, hs, t + 2);
#pragma unroll
            for (int hs = 0; hs < 4; ++hs) stage(Ag, lA, hs, t + 2);
        }
        mfma8(4, 2);                         // register-only, overlaps stage
        if (pf) {
            asm volatile("s_waitcnt vmcnt(8)" ::: "memory");
        } else {
            asm volatile("s_waitcnt vmcnt(0)" ::: "memory");
        }
        __builtin_amdgcn_s_barrier();        // buf[cur^1] resident chip-wide
        asm volatile("" ::: "memory");
    }
}

// ---------------------------------------------------------------------------
// Fused QKV GEMM. Wcat = [3072][1024] (Wq;Wk;Wv). Grid: 768 blocks of 512.
// Epilogue: LDS-bounce for fully-coalesced dwordx4 stores (512B runs/row).
// ---------------------------------------------------------------------------
__global__ __launch_bounds__(512, 2) void gemm_qkv(const u16* __restrict__ A,
                                                   const u16* __restrict__ Wcat,
                                                   const float* __restrict__ bq,
                                                   const float* __restrict__ bk,
                                                   const float* __restrict__ bv,
                                                   u16* __restrict__ qo,
                                                   u16* __restrict__ ko,
                                                   u16* __restrict__ vo) {
    __shared__ __align__(16) u16 As[32768];
    __shared__ __align__(16) u16 Bs[32768];
    const int bid = blockIdx.x;                    // 768 = 64 M-tiles x 12 N-tiles
    const int swz = (bid & 7) * 96 + (bid >> 3);   // XCD swizzle (768 % 8 == 0)
    const int bx  = swz / 12;
    const int byy = swz - bx * 12;
    const long tileM = (long)bx * 256;

    f32x4 acc[8][4] = {};
    gemm256_core(A + (tileM << 10), Wcat + ((long)byy << 18), As, Bs, acc);

    const int tid  = (int)threadIdx.x;
    const int wave = tid >> 6;
    const int lane = tid & 63;
    const int quad = lane >> 4, l15 = lane & 15;
    const int wr = wave >> 2, wc = wave & 3;
    const int mat = byy >> 2;                      // 0:q 1:k 2:v
    const float* bias = (mat == 0) ? bq : (mat == 1) ? bk : bv;
    u16* outp = (mat == 0) ? qo : (mat == 1) ? ko : vo;
    const bool relu = (mat < 2);
    const int ncol0 = (byy & 3) * 256;

    // --- coalesced epilogue: 2 passes of [128 rows x 256 cols] u16 via As ---
    const int rloc = tid >> 5;
    const int c8   = (tid & 31) * 8;
#pragma unroll 1
    for (int pass = 0; pass < 2; ++pass) {
        __syncthreads();
        if (wr == pass) {
#pragma unroll
            for (int i = 0; i < 8; ++i)
#pragma unroll
                for (int j = 0; j < 4; ++j) {
                    const int col = wc * 64 + j * 16 + l15;
                    const float bb = bias[ncol0 + col];
#pragma unroll
                    for (int r = 0; r < 4; ++r) {
                        const int row = i * 16 + quad * 4 + r;
                        float v = acc[i][j][r] + bb;
                        if (relu) v = fmaxf(v, 0.0f);
                        As[row * 256 + col] = f32_to_bf16(v);
                    }
                }
        }
        __syncthreads();
        const long gr0 = tileM + pass * 128;
#pragma unroll
        for (int it = 0; it < 8; ++it) {
            const int row = it * 16 + rloc;
            uint4 t4 = *(const uint4*)&As[row * 256 + c8];
            *(uint4*)&outp[(gr0 + row) * 1024 + ncol0 + c8] = t4;
        }
    }
}

// ---------------------------------------------------------------------------
// Output-projection GEMM (fp32 out). Grid: 256 blocks of 512.
// fp32 stores are 64B-contiguous per 16 lanes (= HBM write granule) - direct.
// ---------------------------------------------------------------------------
__global__ __launch_bounds__(512, 2) void gemm_o(const u16* __restrict__ A,
                                                 const u16* __restrict__ Bw,
                                                 const float* __restrict__ bias,
                                                 float* __restrict__ Cout) {
    __shared__ __align__(16) u16 As[32768];
    __shared__ __align__(16) u16 Bs[32768];
    const int bid = blockIdx.x;                    // 256 = 64 M-tiles x 4 N-tiles
    const int swz = (bid & 7) * 32 + (bid >> 3);   // XCD swizzle (256 % 8 == 0)
    const long tileM = (long)(swz >> 2) * 256;
    const long tileN = (long)(swz & 3) * 256;

    f32x4 acc[8][4] = {};
    gemm256_core(A + (tileM << 10), Bw + (tileN << 10), As, Bs, acc);

    const int wave = (int)threadIdx.x >> 6;
    const int lane = (int)threadIdx.x & 63;
    const int quad = lane >> 4, l15 = lane & 15;
    const int wr = wave >> 2, wc = wave & 3;
#pragma unroll
    for (int j = 0; j < 4; ++j) {
        const long n = tileN + wc * 64 + j * 16 + l15;
        const float bb = bias[n];
#pragma unroll
        for (int i = 0; i < 8; ++i) {
            const long m0 = tileM + wr * 128 + i * 16 + quad * 4;
#pragma unroll
            for (int r = 0; r < 4; ++r)
                Cout[(m0 + r) * 1024 + n] = acc[i][j][r] + bb;
        }
    }
}

// ---------------------------------------------------------------------------
// Stage C (MFMA): per (chunk, head): part[d2=128][n=80] = k_^T @ [v | 1 | 0]
//   over K = 512 l's. 64-l K-tiles: half the syncthreads of the 32-l version,
//   register prefetch of next-kt global loads, same per-l LDS traffic.
// grid (8, 64), 256 threads = 4 waves.
// part layout: [chunk8][head64][128][80] f32.
// ---------------------------------------------------------------------------
__global__ __launch_bounds__(256) void kv_mfma(const u16* __restrict__ kmat,
                                               const u16* __restrict__ vmat,
                                               float* __restrict__ part) {
    __shared__ u16 Ak[64 * 72];   // [d 64][l 64 +8 pad], row stride 144B
    __shared__ u16 Bv[64 * 72];
    const int tid = threadIdx.x;
    const int wave = tid >> 6, lane = tid & 63;
    const int quad = lane >> 4, l15 = lane & 15;
    const int head = blockIdx.y;
    const int b = head >> 4, h = head & 15;
    const int l0 = blockIdx.x * 512;
    const int sl = tid >> 3;          // staging row l 0..31 (and +32)
    const int sc8 = tid & 7;          // staging d-octet 0..7
    const int scol = sl ^ ((sc8 & 3) << 3);   // XOR swizzle col (bit5 untouched)
    const int krow_base = (wave & 1) * 32;
    const bool use_cos = (wave >> 1) != 0;
    const int mbase = wave * 32;

    // sin/cos for l = l0 + kt*64 + kk*32 + quad*8 + e
    // sv/cv: kk=0 lane angles; s2/c2: kk=1 (= +pi/256); advance pi/128 per kt.
    float sv[8], cv[8], s2[8], c2[8];
#pragma unroll
    for (int e = 0; e < 8; e++) {
        float ang = (PI_HALF / 4096.0f) * (float)(l0 + quad * 8 + e + 1);
        sv[e] = sinf(ang); cv[e] = cosf(ang);
        float ang2 = ang + (PI_HALF / 4096.0f) * 32.0f;
        s2[e] = sinf(ang2); c2[e] = cosf(ang2);
    }
    const float cD = 0.99969881869620422f;  // cos(pi/128)
    const float sD = 0.02454122852291229f;  // sin(pi/128)

    bf16x8 onesf;
#pragma unroll
    for (int e = 0; e < 8; e++)
        onesf[e] = (l15 == 0) ? (__bf16)1.0f : (__bf16)0.0f;

    f32x4 acc[2][5] = {};

    long row = ((long)b * 4096 + l0 + sl) * 1024 + h * 64 + sc8 * 8;
    uint4 kkA = *(const uint4*)(kmat + row);
    uint4 vvA = *(const uint4*)(vmat + row);
    uint4 kkB = *(const uint4*)(kmat + row + 32 * 1024);
    uint4 vvB = *(const uint4*)(vmat + row + 32 * 1024);

#pragma unroll 1
    for (int kt = 0; kt < 8; kt++) {
        uint4 kkA_n = {}, vvA_n = {}, kkB_n = {}, vvB_n = {};
        if (kt < 7) {                        // prefetch next kt before writes
            row += 64 * 1024;
            kkA_n = *(const uint4*)(kmat + row);
            vvA_n = *(const uint4*)(vmat + row);
            kkB_n = *(const uint4*)(kmat + row + 32 * 1024);
            vvB_n = *(const uint4*)(vmat + row + 32 * 1024);
        }
        {
            const u16* kp = (const u16*)&kkA;
            const u16* vp = (const u16*)&vvA;
            const u16* kp2 = (const u16*)&kkB;
            const u16* vp2 = (const u16*)&vvB;
#pragma unroll
            for (int e = 0; e < 8; e++) {
                const int d = sc8 * 8 + e;
                Ak[d * 72 + scol]      = kp[e];
                Bv[d * 72 + scol]      = vp[e];
                Ak[d * 72 + scol + 32] = kp2[e];
                Bv[d * 72 + scol + 32] = vp2[e];
            }
        }
        __syncthreads();

        bf16x8 af[2][2];
#pragma unroll
        for (int i = 0; i < 2; i++) {
            const int d = krow_base + i * 16 + l15;
            const int q2 = (quad ^ ((d >> 3) & 3)) * 8;
#pragma unroll
            for (int kk = 0; kk < 2; kk++) {
                bf16x8 raw = *(const bf16x8*)&Ak[d * 72 + kk * 32 + q2];
                bf16x8 sc;
#pragma unroll
                for (int e = 0; e < 8; e++) {
                    const float s = use_cos ? (kk ? c2[e] : cv[e])
                                            : (kk ? s2[e] : sv[e]);
                    sc[e] = (__bf16)((float)raw[e] * s);
                }
                af[i][kk] = sc;
            }
        }
        bf16x8 bfr[5][2];
#pragma unroll
        for (int j = 0; j < 4; j++) {
            const int n = j * 16 + l15;
            const int q2 = (quad ^ ((n >> 3) & 3)) * 8;
            bfr[j][0] = *(const bf16x8*)&Bv[n * 72 + q2];
            bfr[j][1] = *(const bf16x8*)&Bv[n * 72 + 32 + q2];
        }
        bfr[4][0] = onesf; bfr[4][1] = onesf;
#pragma unroll
        for (int i = 0; i < 2; i++)
#pragma unroll
            for (int j = 0; j < 5; j++) {
                acc[i][j] = __builtin_amdgcn_mfma_f32_16x16x32_bf16(
                    af[i][0], bfr[j][0], acc[i][j], 0, 0, 0);
                acc[i][j] = __builtin_amdgcn_mfma_f32_16x16x32_bf16(
                    af[i][1], bfr[j][1], acc[i][j], 0, 0, 0);
            }

        // advance angles by pi/128 (64 l's)
#pragma unroll
        for (int e = 0; e < 8; e++) {
            float ns = sv[e] * cD + cv[e] * sD;
            cv[e] = cv[e] * cD - sv[e] * sD;
            sv[e] = ns;
            ns = s2[e] * cD + c2[e] * sD;
            c2[e] = c2[e] * cD - s2[e] * sD;
            s2[e] = ns;
        }
        __syncthreads();
        kkA = kkA_n; vvA = vvA_n; kkB = kkB_n; vvB = vvB_n;
    }

    float* op = part + ((long)blockIdx.x * 64 + head) * 10240;
#pragma unroll
    for (int i = 0; i < 2; i++)
#pragma unroll
        for (int j = 0; j < 5; j++)
#pragma unroll
            for (int r = 0; r < 4; r++)
                op[(mbase + i * 16 + quad * 4 + r) * 80 + j * 16 + l15] = acc[i][j][r];
}

// ---------------------------------------------------------------------------
// Stage C2: sum 8 chunk-partials, transpose to Bt[head][n=80][d2=128] bf16.
// grid (4 d2-tiles of 32, 64 heads), 256 threads.
// ---------------------------------------------------------------------------
__global__ __launch_bounds__(256) void kv_reduce_t(const float* __restrict__ part,
                                                   u16* __restrict__ Bt) {
    __shared__ float accs[32 * 81];
    const int head = blockIdx.y, d2t = blockIdx.x;
    const float* bp = part + (long)head * 10240 + d2t * 32 * 80;
    for (int idx = threadIdx.x; idx < 2560; idx += 256) {
        float s = 0.0f;
#pragma unroll
        for (int c = 0; c < 8; c++) s += bp[(long)c * 655360 + idx];
        const int d2 = idx / 80, n = idx - d2 * 80;
        accs[d2 * 81 + n] = s;
    }
    __syncthreads();
    for (int idx = threadIdx.x; idx < 2560; idx += 256) {
        const int n = idx >> 5, d2 = idx & 31;
        Bt[(long)head * 10240 + n * 128 + d2t * 32 + d2] = f32_to_bf16(accs[d2 * 81 + n]);
    }
}

// ---------------------------------------------------------------------------
// Stage D: per-head MFMA GEMM: attn[l, 0..79] = q_[l, 0..127] @ Bt^T
// 256 q-rows per block (Bt staged once per 2 q-tiles, half the blocks).
// Epilogue: LDS-bounce for coalesced 128B-per-row dwordx4 stores.
// grid (16, 64), 256 threads.
// ---------------------------------------------------------------------------
__global__ __launch_bounds__(256) void attn_mfma(const u16* __restrict__ qb,
                                                 const u16* __restrict__ Bt,
                                                 u16* __restrict__ merged) {
    __shared__ __align__(16) u16 As[128 * 72];   // q tile [l][64], stride 72
    __shared__ __align__(16) u16 Bs[80 * 136];   // Bt tile [n][128], stride 136
    const int tid = threadIdx.x;
    const int wave = tid >> 6, lane = tid & 63;
    const int quad = lane >> 4, l15 = lane & 15;
    const int head = blockIdx.y;
    const int b = head >> 4, h = head & 15;
    const int tm0 = blockIdx.x * 256;
    const long b4 = (long)b * 4096;
    const int wm = wave * 32;

    // Bt tile staged ONCE for both q-halves
    for (int c = tid; c < 1280; c += 256) {
        const int row = c >> 4, c16 = c & 15;
        uint4 t = *(const uint4*)(Bt + (long)head * 10240 + row * 128 + c16 * 8);
        *(uint4*)&Bs[row * 136 + c16 * 8] = t;
    }

#pragma unroll 1
    for (int half = 0; half < 2; ++half) {
        const int tm = tm0 + half * 128;
        __syncthreads();   // Bs ready / prior copy-out of As done
        for (int c = tid; c < 1024; c += 256) {
            const int row = c >> 3, c8 = c & 7;
            uint4 t = *(const uint4*)(qb + (b4 + tm + row) * 1024 + h * 64 + c8 * 8);
            *(uint4*)&As[row * 72 + c8 * 8] = t;
        }
        float snl[2], csl[2];
#pragma unroll
        for (int i = 0; i < 2; i++) {
            const int l = tm + wm + i * 16 + l15;
            const float idx = PI_HALF * (float)(l + 1) * (1.0f / 4096.0f);
            snl[i] = sinf(idx); csl[i] = cosf(idx);
        }
        __syncthreads();

        f32x4 acc[2][5] = {};
#pragma unroll
        for (int kb = 0; kb < 4; kb++) {
            const int qc = (kb & 1) * 32 + quad * 8;
            bf16x8 af[2];
#pragma unroll
            for (int i = 0; i < 2; i++) {
                bf16x8 raw = *(const bf16x8*)&As[(wm + i * 16 + l15) * 72 + qc];
                const float s = (kb < 2) ? snl[i] : csl[i];
                bf16x8 sc;
#pragma unroll
                for (int e = 0; e < 8; e++) sc[e] = (__bf16)((float)raw[e] * s);
                af[i] = sc;
            }
            bf16x8 bf[5];
#pragma unroll
            for (int j = 0; j < 5; j++)
                bf[j] = *(const bf16x8*)&Bs[(j * 16 + l15) * 136 + kb * 32 + quad * 8];
#pragma unroll
            for (int i = 0; i < 2; i++)
#pragma unroll
                for (int j = 0; j < 5; j++)
                    acc[i][j] = __builtin_amdgcn_mfma_f32_16x16x32_bf16(
                        af[i], bf[j], acc[i][j], 0, 0, 0);
        }

        // normalize + dump to LDS (reuse As as [128 rows][64 cols] u16)
        __syncthreads();
#pragma unroll
        for (int i = 0; i < 2; i++) {
            float z[4];
#pragma unroll
            for (int r = 0; r < 4; r++) {
                const float den = __shfl(acc[i][4][r], lane & 0x30, 64);
                z[r] = 1.0f / fmaxf(den, EPS_Z);
            }
#pragma unroll
            for (int j = 0; j < 4; j++)
#pragma unroll
                for (int r = 0; r < 4; r++) {
                    const int row = wm + i * 16 + quad * 4 + r;
                    As[row * 64 + j * 16 + l15] = f32_to_bf16(acc[i][j][r] * z[r]);
                }
        }
        __syncthreads();
        // coalesced copy-out: 128 rows x 128B; 256 threads = 32 rows/iter
        const int rloc = tid >> 3, c8o = (tid & 7) * 8;
#pragma unroll
        for (int it = 0; it < 4; ++it) {
            const int row = it * 32 + rloc;
            uint4 t4 = *(const uint4*)&As[row * 64 + c8o];
            *(uint4*)&merged[(b4 + tm + row) * 1024 + h * 64 + c8o] = t4;
        }
    }
}

// ---------------------------------------------------------------------------
extern "C" void kernel_launch(void* const* d_in, const int* in_sizes, int n_in,
                              void* d_out, int out_size, void* d_ws, size_t ws_size,
                              hipStream_t stream) {
    (void)in_sizes; (void)n_in; (void)out_size; (void)ws_size;
    const float* x  = (const float*)d_in[0];
    const float* Wq = (const float*)d_in[1];
    const float* bq = (const float*)d_in[2];
    const float* Wk = (const float*)d_in[3];
    const float* bk = (const float*)d_in[4];
    const float* Wv = (const float*)d_in[5];
    const float* bv = (const float*)d_in[6];
    const float* Wo = (const float*)d_in[7];
    const float* bo = (const float*)d_in[8];
    float* out = (float*)d_out;

    const int E = 1024;
    char* ws = (char*)d_ws;
    const size_t MB = 1048576;
    u16* xb   = (u16*)(ws);              // 32 MiB; dead after QKV GEMM -> part
    u16* qb   = (u16*)(ws + 32 * MB);
    u16* kb   = (u16*)(ws + 64 * MB);    // dead after kv_mfma -> merged
    u16* vb   = (u16*)(ws + 96 * MB);
    u16* wcat = (u16*)(ws + 128 * MB);   // Wq;Wk;Wv;Wo bf16, 8 MiB
    u16* wob  = wcat + 3 * (size_t)E * E;
    u16* Btb  = (u16*)(ws + 136 * MB);   // 1.25 MiB
    float* part = (float*)xb;            // 8*64*10240*4 = 20 MiB
    u16* mergedb = kb;

    cvt_all<<<dim3(20480), dim3(256), 0, stream>>>(x, Wq, Wk, Wv, Wo, xb, wcat);

    gemm_qkv<<<dim3(768), dim3(512), 0, stream>>>(xb, wcat, bq, bk, bv, qb, kb, vb);

    kv_mfma<<<dim3(8, 64), dim3(256), 0, stream>>>(kb, vb, part);
    kv_reduce_t<<<dim3(4, 64), dim3(256), 0, stream>>>(part, Btb);
    attn_mfma<<<dim3(16, 64), dim3(256), 0, stream>>>(qb, Btb, mergedb);

    gemm_o<<<dim3(256), dim3(512), 0, stream>>>(mergedb, wob, bo, out);
}